// Round 7
// baseline (32330.167 us; speedup 1.0000x reference)
//
#include <hip/hip_runtime.h>
#include <hip/hip_bf16.h>

typedef __attribute__((ext_vector_type(8))) short short8;
typedef __attribute__((ext_vector_type(4))) float f32x4;

#define T_STEPS 4096
#define EMBD 2048
#define OUTD 2048
#define N4 8192          // 4*OUTD
#define NBLK 128         // scan blocks
#define WPB 16           // waves per scan block (1024 threads)

#define AL64(p) __hip_atomic_load((p), __ATOMIC_RELAXED, __HIP_MEMORY_SCOPE_AGENT)

__device__ __forceinline__ unsigned int rn_bf16_bits(float f) {
    unsigned int u = __float_as_uint(f);
    u += 0x7fffu + ((u >> 16) & 1u);      // RN-even to bf16
    return u >> 16;
}

// ---------------- fp32 -> bf16 convert ----------------
__global__ void f32_to_bf16_kernel(const float* __restrict__ in,
                                   __hip_bfloat16* __restrict__ out, int n) {
    int i = blockIdx.x * blockDim.x + threadIdx.x;
    int stride = gridDim.x * blockDim.x;
    for (int idx = i * 4; idx < n; idx += stride * 4) {
        float4 v = *(const float4*)(in + idx);
        out[idx + 0] = __float2bfloat16(v.x);
        out[idx + 1] = __float2bfloat16(v.y);
        out[idx + 2] = __float2bfloat16(v.z);
        out[idx + 3] = __float2bfloat16(v.w);
    }
}

// ---------------- prep: init packed h buffer {h_fp32 | tag32} (R4 protocol) ----
__global__ void prep_kernel(const float* __restrict__ init_hid,
                            unsigned long long* __restrict__ hbuf2) {
    int i = blockIdx.x * blockDim.x + threadIdx.x;
    if (i < OUTD) {
        unsigned long long hb = (unsigned long long)__float_as_uint(init_hid[i]);
        hbuf2[i] = (hb << 32) | 0ull;   // parity 0: h = init_hid, tag = 0
        hbuf2[OUTD + i] = 0ull;         // parity 1: tag 0 (never matches t>=1)
    }
}

// ---------------- GEMM: xp = A @ W_ih^T + (b_ih + b_hh), bf16 out ----------------
__global__ __launch_bounds__(256) void gemm_xproj(
    const __hip_bfloat16* __restrict__ A, const __hip_bfloat16* __restrict__ B,
    const float* __restrict__ b_ih, const float* __restrict__ b_hh,
    __hip_bfloat16* __restrict__ xp) {
    __shared__ __hip_bfloat16 As[64][32];
    __shared__ __hip_bfloat16 Bs[64][32];
    const int bm = blockIdx.x, bn = blockIdx.y;
    const int tid = threadIdx.x;
    const int w = tid >> 6, l = tid & 63;
    const int wr = w >> 1, wc = w & 1;
    const int srow = tid >> 2, skc = tid & 3;

    f32x4 acc[2][2] = {};

    const __hip_bfloat16* Abase = A + (size_t)(bm * 64 + srow) * EMBD + skc * 8;
    const __hip_bfloat16* Bbase = B + (size_t)(bn * 64 + srow) * EMBD + skc * 8;

    const int krow = l >> 4;
    const int fr = l & 15;

    for (int k0 = 0; k0 < EMBD; k0 += 32) {
        __syncthreads();
        *(short8*)(&As[srow][skc * 8]) = *(const short8*)(Abase + k0);
        *(short8*)(&Bs[srow][skc * 8]) = *(const short8*)(Bbase + k0);
        __syncthreads();

        short8 afrag[2], bfrag[2];
#pragma unroll
        for (int m = 0; m < 2; ++m)
            afrag[m] = *(const short8*)(&As[wr * 32 + m * 16 + fr][krow * 8]);
#pragma unroll
        for (int n = 0; n < 2; ++n)
            bfrag[n] = *(const short8*)(&Bs[wc * 32 + n * 16 + fr][krow * 8]);
#pragma unroll
        for (int m = 0; m < 2; ++m)
#pragma unroll
            for (int n = 0; n < 2; ++n)
                acc[m][n] = __builtin_amdgcn_mfma_f32_16x16x32_bf16(
                    afrag[m], bfrag[n], acc[m][n], 0, 0, 0);
    }

    const int fq = l >> 4;
#pragma unroll
    for (int m = 0; m < 2; ++m) {
#pragma unroll
        for (int n = 0; n < 2; ++n) {
            int col = bn * 64 + wc * 32 + n * 16 + fr;
            float bias = b_ih[col] + b_hh[col];
#pragma unroll
            for (int r = 0; r < 4; ++r) {
                int row = bm * 64 + wr * 32 + m * 16 + fq * 4 + r;
                xp[(size_t)row * N4 + col] = __float2bfloat16(acc[m][n][r] + bias);
            }
        }
    }
}

// ---------------- sequential LSTM scan ----------------
// 128 blocks x 1024 threads (16 waves). Wave w of block b owns j = 16b + w.
// R4-exact broadcast protocol: u64 packed {h_fp32 | tag32}, publish via
// agent-scope atomic exchange (RMW executes at the coherence point), poll via
// unconditional parallel relaxed atomic loads (2 words/lane, 128 words/wave).
// Halved block count halves the aggregate poll traffic at the MALL (the
// R3->R4 scaling showed the scan is contention-limited, not latency-limited).
// W_hh held as packed bf16 pairs (64 VGPR/lane) to fit 16 waves/CU @ <=128 VGPR.
__global__ __launch_bounds__(1024, 4) void lstm_scan(
    const float* __restrict__ W_hh,            // [8192][2048] fp32
    const __hip_bfloat16* __restrict__ xp,     // [4096][8192] bf16
    const float* __restrict__ init_cell,
    unsigned long long* hbuf2,                 // [2][2048] packed {h|tag}
    float* __restrict__ out)                   // [4096] = h(2048) ++ c(2048)
{
    __shared__ float hs[2][OUTD];              // 16 KiB double-buffered h (fp32)
    const int tid = threadIdx.x;
    const int wave = tid >> 6;
    const int lane = tid & 63;
    const int j = blockIdx.x * WPB + wave;
    const int chunk = wave * 128 + lane;       // this lane's poll base word

    // W_hh rows for gates i,f,g,o of index j, packed bf16 pairs:
    // Wpk[rr][kk] = { bf16(W[kk*64+lane])      in bits[15:0],
    //                 bf16(W[(kk+16)*64+lane]) in bits[31:16] }
    unsigned int Wpk[4][16];
#pragma unroll
    for (int rr = 0; rr < 4; ++rr) {
        const float* wrow = W_hh + (size_t)(rr * OUTD + j) * OUTD;
#pragma unroll
        for (int kk = 0; kk < 16; ++kk) {
            unsigned int lo = rn_bf16_bits(wrow[kk * 64 + lane]);
            unsigned int hi = rn_bf16_bits(wrow[(kk + 16) * 64 + lane]);
            Wpk[rr][kk] = (hi << 16) | lo;
        }
    }
    float c = init_cell[j];

    for (int t = 0; t < T_STEPS; ++t) {
        const unsigned int tag = (unsigned int)t;
        const int pr = t & 1;
        unsigned long long* hsrc = hbuf2 + (size_t)pr * OUTD;
        unsigned long long* p0 = &hsrc[chunk];
        unsigned long long* p1 = &hsrc[chunk + 64];

        // xp values for this step (independent of h -> issue early)
        const __hip_bfloat16* xpt = xp + (size_t)t * N4 + j;
        float xpi = __bfloat162float(xpt[0]);
        float xpf = __bfloat162float(xpt[OUTD]);
        float xpg = __bfloat162float(xpt[2 * OUTD]);
        float xpo = __bfloat162float(xpt[3 * OUTD]);

        // R4-style poll: unconditional parallel loads, sleep only when starved.
        unsigned long long w0, w1;
        {
            int spins = 0;
            bool rmw = false;      // deadlock insurance: flip to MALL RMW reads
            while (true) {
                if (!rmw) {
                    w0 = AL64(p0);
                    w1 = AL64(p1);
                } else {
                    w0 = __hip_atomic_fetch_add(p0, 0ull, __ATOMIC_RELAXED, __HIP_MEMORY_SCOPE_AGENT);
                    w1 = __hip_atomic_fetch_add(p1, 0ull, __ATOMIC_RELAXED, __HIP_MEMORY_SCOPE_AGENT);
                }
                bool ok = ((unsigned int)w0 == tag) & ((unsigned int)w1 == tag);
                if (__all(ok)) break;
                if (++spins > 8) __builtin_amdgcn_s_sleep(1);
                if (spins > 100000) rmw = true;
            }
        }
        hs[pr][chunk]      = __uint_as_float((unsigned int)(w0 >> 32));
        hs[pr][chunk + 64] = __uint_as_float((unsigned int)(w1 >> 32));
        __syncthreads();

        // GEMV from LDS: 4 gate rows; W unpacked from bf16 pairs
        float acc0 = 0.f, acc1 = 0.f, acc2 = 0.f, acc3 = 0.f;
#pragma unroll
        for (int kk = 0; kk < 16; ++kk) {
            float hlo = hs[pr][kk * 64 + lane];
            float hhi = hs[pr][(kk + 16) * 64 + lane];
#pragma unroll
            for (int rr = 0; rr < 4; ++rr) {
                unsigned int u = Wpk[rr][kk];
                float wlo = __uint_as_float(u << 16);
                float whi = __uint_as_float(u & 0xffff0000u);
                float a = (rr == 0) ? acc0 : (rr == 1) ? acc1 : (rr == 2) ? acc2 : acc3;
                a += wlo * hlo + whi * hhi;
                if (rr == 0) acc0 = a; else if (rr == 1) acc1 = a;
                else if (rr == 2) acc2 = a; else acc3 = a;
            }
        }
        // 64-lane butterfly reduce
#pragma unroll
        for (int s = 32; s >= 1; s >>= 1) {
            acc0 += __shfl_xor(acc0, s);
            acc1 += __shfl_xor(acc1, s);
            acc2 += __shfl_xor(acc2, s);
            acc3 += __shfl_xor(acc3, s);
        }

        float gi = __builtin_amdgcn_rcpf(1.f + __expf(-(xpi + acc0)));
        float gf = __builtin_amdgcn_rcpf(1.f + __expf(-(xpf + acc1)));
        float gg = 1.f - 2.f * __builtin_amdgcn_rcpf(__expf(2.f * (xpg + acc2)) + 1.f);
        float go = __builtin_amdgcn_rcpf(1.f + __expf(-(xpo + acc3)));
        c = gf * c + gi * gg;
        float h = go * (1.f - 2.f * __builtin_amdgcn_rcpf(__expf(2.f * c) + 1.f));

        if (t == T_STEPS - 1) {
            if (lane == 0) { out[j] = h; out[OUTD + j] = c; }
        } else if (lane == 0) {
            unsigned long long packed =
                ((unsigned long long)__float_as_uint(h) << 32) |
                (unsigned long long)(unsigned int)(t + 1);
            // RMW publish: executes at the coherence point, no cache ops needed
            (void)__hip_atomic_exchange(&hbuf2[(size_t)((t + 1) & 1) * OUTD + j],
                                        packed, __ATOMIC_RELAXED,
                                        __HIP_MEMORY_SCOPE_AGENT);
        }
        // No second barrier needed: hs[pr] is next overwritten at step t+2,
        // which requires every wave of this block past the barrier at t+1.
    }
}

extern "C" void kernel_launch(void* const* d_in, const int* in_sizes, int n_in,
                              void* d_out, int out_size, void* d_ws, size_t ws_size,
                              hipStream_t stream) {
    (void)in_sizes; (void)n_in; (void)out_size; (void)ws_size;
    const float* stacked   = (const float*)d_in[0];
    const float* init_hid  = (const float*)d_in[1];
    const float* init_cell = (const float*)d_in[2];
    const float* W_ih      = (const float*)d_in[3];
    const float* W_hh      = (const float*)d_in[4];
    const float* b_ih      = (const float*)d_in[5];
    const float* b_hh      = (const float*)d_in[6];
    float* out = (float*)d_out;

    char* ws = (char*)d_ws;
    __hip_bfloat16* xp  = (__hip_bfloat16*)ws;                        // 67,108,864 B
    __hip_bfloat16* A16 = (__hip_bfloat16*)(ws + 67108864);           // 16,777,216 B
    __hip_bfloat16* W16 = (__hip_bfloat16*)(ws + 83886080);           // 33,554,432 B
    unsigned long long* hbuf2 = (unsigned long long*)(ws + 117440512);// 32,768 B

    f32_to_bf16_kernel<<<4096, 256, 0, stream>>>(stacked, A16, T_STEPS * EMBD);
    f32_to_bf16_kernel<<<8192, 256, 0, stream>>>(W_ih, W16, N4 * EMBD);
    prep_kernel<<<8, 256, 0, stream>>>(init_hid, hbuf2);
    gemm_xproj<<<dim3(64, 128), 256, 0, stream>>>(A16, W16, b_ih, b_hh, xp);
    lstm_scan<<<NBLK, 1024, 0, stream>>>(W_hh, xp, init_cell, hbuf2, out);
}

// Round 8
// 7954.992 us; speedup vs baseline: 4.0641x; 4.0641x over previous
//
#include <hip/hip_runtime.h>
#include <hip/hip_bf16.h>

typedef __attribute__((ext_vector_type(8))) short short8;
typedef __attribute__((ext_vector_type(4))) float f32x4;

#define T_STEPS 4096
#define EMBD 2048
#define OUTD 2048
#define N4 8192          // 4*OUTD
#define NBLK 256
#define WPB 8            // waves per block in scan

#define AL(p) __hip_atomic_load((p), __ATOMIC_RELAXED, __HIP_MEMORY_SCOPE_AGENT)

__device__ __forceinline__ unsigned int pack_h(float h, unsigned int tag) {
    // round-to-nearest-even bf16 in hi16, tag in lo16
    unsigned int u = __float_as_uint(h);
    u += 0x7fffu + ((u >> 16) & 1u);
    return (u & 0xffff0000u) | (tag & 0xffffu);
}

// ---------------- fp32 -> bf16 convert ----------------
__global__ void f32_to_bf16_kernel(const float* __restrict__ in,
                                   __hip_bfloat16* __restrict__ out, int n) {
    int i = blockIdx.x * blockDim.x + threadIdx.x;
    int stride = gridDim.x * blockDim.x;
    for (int idx = i * 4; idx < n; idx += stride * 4) {
        float4 v = *(const float4*)(in + idx);
        out[idx + 0] = __float2bfloat16(v.x);
        out[idx + 1] = __float2bfloat16(v.y);
        out[idx + 2] = __float2bfloat16(v.z);
        out[idx + 3] = __float2bfloat16(v.w);
    }
}

// ---------------- prep: init packed h buffer {bf16 h | tag16} ----------------
__global__ void prep_kernel(const float* __restrict__ init_hid,
                            unsigned int* __restrict__ hbuf2) {
    int i = blockIdx.x * blockDim.x + threadIdx.x;
    if (i < OUTD) {
        hbuf2[i] = pack_h(init_hid[i], 0u);   // parity 0: h = init_hid, tag = 0
        hbuf2[OUTD + i] = 0u;                 // parity 1: tag 0 (never matches t>=1)
    }
}

// ---------------- GEMM: xp = A @ W_ih^T + (b_ih + b_hh), bf16 out ----------------
__global__ __launch_bounds__(256) void gemm_xproj(
    const __hip_bfloat16* __restrict__ A, const __hip_bfloat16* __restrict__ B,
    const float* __restrict__ b_ih, const float* __restrict__ b_hh,
    __hip_bfloat16* __restrict__ xp) {
    __shared__ __hip_bfloat16 As[64][32];
    __shared__ __hip_bfloat16 Bs[64][32];
    const int bm = blockIdx.x, bn = blockIdx.y;
    const int tid = threadIdx.x;
    const int w = tid >> 6, l = tid & 63;
    const int wr = w >> 1, wc = w & 1;
    const int srow = tid >> 2, skc = tid & 3;

    f32x4 acc[2][2] = {};

    const __hip_bfloat16* Abase = A + (size_t)(bm * 64 + srow) * EMBD + skc * 8;
    const __hip_bfloat16* Bbase = B + (size_t)(bn * 64 + srow) * EMBD + skc * 8;

    const int krow = l >> 4;
    const int fr = l & 15;

    for (int k0 = 0; k0 < EMBD; k0 += 32) {
        __syncthreads();
        *(short8*)(&As[srow][skc * 8]) = *(const short8*)(Abase + k0);
        *(short8*)(&Bs[srow][skc * 8]) = *(const short8*)(Bbase + k0);
        __syncthreads();

        short8 afrag[2], bfrag[2];
#pragma unroll
        for (int m = 0; m < 2; ++m)
            afrag[m] = *(const short8*)(&As[wr * 32 + m * 16 + fr][krow * 8]);
#pragma unroll
        for (int n = 0; n < 2; ++n)
            bfrag[n] = *(const short8*)(&Bs[wc * 32 + n * 16 + fr][krow * 8]);
#pragma unroll
        for (int m = 0; m < 2; ++m)
#pragma unroll
            for (int n = 0; n < 2; ++n)
                acc[m][n] = __builtin_amdgcn_mfma_f32_16x16x32_bf16(
                    afrag[m], bfrag[n], acc[m][n], 0, 0, 0);
    }

    const int fq = l >> 4;
#pragma unroll
    for (int m = 0; m < 2; ++m) {
#pragma unroll
        for (int n = 0; n < 2; ++n) {
            int col = bn * 64 + wc * 32 + n * 16 + fr;
            float bias = b_ih[col] + b_hh[col];
#pragma unroll
            for (int r = 0; r < 4; ++r) {
                int row = bm * 64 + wr * 32 + m * 16 + fq * 4 + r;
                xp[(size_t)row * N4 + col] = __float2bfloat16(acc[m][n][r] + bias);
            }
        }
    }
}

// ---------------- sequential LSTM scan ----------------
// R4-EXACT structure: 256 blocks x 512 threads (8 waves), wave w of block b
// owns j = 8b + w; cooperative poll (8 waves x disjoint 256-word chunks,
// 4 words/lane, UNCONDITIONAL parallel loads); deposit to double-buffered LDS;
// barrier; GEMV from LDS with fp32 W in registers; publish via agent-scope
// atomic exchange. SINGLE CHANGE vs R4: broadcast word is u32 {bf16 h|tag16}
// instead of u64 {fp32 h|tag32} -> per-round MALL line traffic halves.
__global__ __launch_bounds__(512, 2) void lstm_scan(
    const float* __restrict__ W_hh,            // [8192][2048] fp32
    const __hip_bfloat16* __restrict__ xp,     // [4096][8192] bf16
    const float* __restrict__ init_cell,
    unsigned int* hbuf2,                       // [2][2048] packed {bf16 h|tag16}
    float* __restrict__ out)                   // [4096] = h(2048) ++ c(2048)
{
    __shared__ float hs[2][OUTD];              // 16 KiB double-buffered h (fp32)
    const int tid = threadIdx.x;
    const int wave = tid >> 6;
    const int lane = tid & 63;
    const int j = blockIdx.x * WPB + wave;
    const int chunk = wave * 256 + lane;       // this lane's poll base word

    // W_hh rows for gates i,f,g,o of index j; lane holds k = kk*64 + lane
    float Wreg[4][32];
#pragma unroll
    for (int rr = 0; rr < 4; ++rr) {
        const float* wrow = W_hh + (size_t)(rr * OUTD + j) * OUTD;
#pragma unroll
        for (int kk = 0; kk < 32; ++kk)
            Wreg[rr][kk] = wrow[kk * 64 + lane];
    }
    float c = init_cell[j];

    for (int t = 0; t < T_STEPS; ++t) {
        const unsigned int tag = (unsigned int)t;
        const int pr = t & 1;
        unsigned int* hsrc = hbuf2 + (size_t)pr * OUTD;

        // xp values for this step (independent of h -> issue early)
        const __hip_bfloat16* xpt = xp + (size_t)t * N4 + j;
        float xpi = __bfloat162float(xpt[0]);
        float xpf = __bfloat162float(xpt[OUTD]);
        float xpg = __bfloat162float(xpt[2 * OUTD]);
        float xpo = __bfloat162float(xpt[3 * OUTD]);

        // R4-exact cooperative poll: unconditional parallel loads.
        unsigned int w0, w1, w2, w3;
        {
            int spins = 0;
            bool rmw = false;      // deadlock insurance: flip to MALL RMW reads
            while (true) {
                if (!rmw) {
                    w0 = AL(&hsrc[chunk]);
                    w1 = AL(&hsrc[chunk + 64]);
                    w2 = AL(&hsrc[chunk + 128]);
                    w3 = AL(&hsrc[chunk + 192]);
                } else {
                    w0 = __hip_atomic_fetch_add(&hsrc[chunk],       0u, __ATOMIC_RELAXED, __HIP_MEMORY_SCOPE_AGENT);
                    w1 = __hip_atomic_fetch_add(&hsrc[chunk + 64],  0u, __ATOMIC_RELAXED, __HIP_MEMORY_SCOPE_AGENT);
                    w2 = __hip_atomic_fetch_add(&hsrc[chunk + 128], 0u, __ATOMIC_RELAXED, __HIP_MEMORY_SCOPE_AGENT);
                    w3 = __hip_atomic_fetch_add(&hsrc[chunk + 192], 0u, __ATOMIC_RELAXED, __HIP_MEMORY_SCOPE_AGENT);
                }
                bool ok = ((w0 & 0xffffu) == tag) & ((w1 & 0xffffu) == tag) &
                          ((w2 & 0xffffu) == tag) & ((w3 & 0xffffu) == tag);
                if (__all(ok)) break;
                if (++spins > 8) __builtin_amdgcn_s_sleep(1);
                if (spins > 100000) rmw = true;
            }
        }
        // decode bf16 (hi16) -> fp32, deposit to LDS
        hs[pr][chunk]       = __uint_as_float(w0 & 0xffff0000u);
        hs[pr][chunk + 64]  = __uint_as_float(w1 & 0xffff0000u);
        hs[pr][chunk + 128] = __uint_as_float(w2 & 0xffff0000u);
        hs[pr][chunk + 192] = __uint_as_float(w3 & 0xffff0000u);
        __syncthreads();

        // GEMV from LDS: 4 gate rows, k strided by 64 across lanes
        float acc0 = 0.f, acc1 = 0.f, acc2 = 0.f, acc3 = 0.f;
#pragma unroll
        for (int kk = 0; kk < 32; ++kk) {
            float hval = hs[pr][kk * 64 + lane];
            acc0 += Wreg[0][kk] * hval;
            acc1 += Wreg[1][kk] * hval;
            acc2 += Wreg[2][kk] * hval;
            acc3 += Wreg[3][kk] * hval;
        }
        // 64-lane butterfly reduce
#pragma unroll
        for (int s = 32; s >= 1; s >>= 1) {
            acc0 += __shfl_xor(acc0, s);
            acc1 += __shfl_xor(acc1, s);
            acc2 += __shfl_xor(acc2, s);
            acc3 += __shfl_xor(acc3, s);
        }

        float gi = __builtin_amdgcn_rcpf(1.f + __expf(-(xpi + acc0)));
        float gf = __builtin_amdgcn_rcpf(1.f + __expf(-(xpf + acc1)));
        float gg = 1.f - 2.f * __builtin_amdgcn_rcpf(__expf(2.f * (xpg + acc2)) + 1.f);
        float go = __builtin_amdgcn_rcpf(1.f + __expf(-(xpo + acc3)));
        c = gf * c + gi * gg;
        float h = go * (1.f - 2.f * __builtin_amdgcn_rcpf(__expf(2.f * c) + 1.f));

        if (t == T_STEPS - 1) {
            if (lane == 0) { out[j] = h; out[OUTD + j] = c; }
        } else if (lane == 0) {
            unsigned int packed = pack_h(h, (unsigned int)(t + 1));
            // RMW publish: executes at the coherence point, no cache ops needed
            (void)__hip_atomic_exchange(&hbuf2[(size_t)((t + 1) & 1) * OUTD + j],
                                        packed, __ATOMIC_RELAXED,
                                        __HIP_MEMORY_SCOPE_AGENT);
        }
        // No second barrier needed: hs[pr] is next overwritten at step t+2,
        // which globally requires every wave to have finished step t first.
    }
}

extern "C" void kernel_launch(void* const* d_in, const int* in_sizes, int n_in,
                              void* d_out, int out_size, void* d_ws, size_t ws_size,
                              hipStream_t stream) {
    (void)in_sizes; (void)n_in; (void)out_size; (void)ws_size;
    const float* stacked   = (const float*)d_in[0];
    const float* init_hid  = (const float*)d_in[1];
    const float* init_cell = (const float*)d_in[2];
    const float* W_ih      = (const float*)d_in[3];
    const float* W_hh      = (const float*)d_in[4];
    const float* b_ih      = (const float*)d_in[5];
    const float* b_hh      = (const float*)d_in[6];
    float* out = (float*)d_out;

    char* ws = (char*)d_ws;
    __hip_bfloat16* xp  = (__hip_bfloat16*)ws;                        // 67,108,864 B
    __hip_bfloat16* A16 = (__hip_bfloat16*)(ws + 67108864);           // 16,777,216 B
    __hip_bfloat16* W16 = (__hip_bfloat16*)(ws + 83886080);           // 33,554,432 B
    unsigned int* hbuf2 = (unsigned int*)(ws + 117440512);            // 16,384 B

    f32_to_bf16_kernel<<<4096, 256, 0, stream>>>(stacked, A16, T_STEPS * EMBD);
    f32_to_bf16_kernel<<<8192, 256, 0, stream>>>(W_ih, W16, N4 * EMBD);
    prep_kernel<<<8, 256, 0, stream>>>(init_hid, hbuf2);
    gemm_xproj<<<dim3(64, 128), 256, 0, stream>>>(A16, W16, b_ih, b_hh, xp);
    lstm_scan<<<NBLK, 512, 0, stream>>>(W_hh, xp, init_cell, hbuf2, out);
}